// Round 2
// baseline (1049.530 us; speedup 1.0000x reference)
//
#include <hip/hip_runtime.h>
#include <math.h>

// DIN attention: per (b,s): MLP(concat[q,k,q*k,q-k]) -> score; masked softmax; attn@keys.
// Decomposition: feats@W0 = q@(W0q+W0d) + k@(W0k-W0d) + (q*k)@W0p
//   = A[b,h] (per-b vector) + k @ M[b] (per-b 64x128 matrix)
// => layer1 K: 256 -> 64. Total ~30 GFLOP f32.

#define B_TOT 8192
#define SEQ 100
#define EDIM 64
#define H1D 128
#define H2D 64

__global__ __launch_bounds__(256, 2)
void din_fused(const float* __restrict__ query,
               const float* __restrict__ keys,
               const int* __restrict__ klen,
               const float* __restrict__ W0,
               const float* __restrict__ b0,
               const float* __restrict__ W1,
               const float* __restrict__ b1,
               const float* __restrict__ W2,
               const float* __restrict__ b2,
               float* __restrict__ out,
               float* __restrict__ attn)
{
    const int b = blockIdx.x;
    const int t = threadIdx.x;
    const int lane = t & 63;
    const int wave = t >> 6;

    __shared__ float q_lds[EDIM];
    __shared__ float A_h[H1D];
    __shared__ float MT[H1D][65];          // MT[h][e], pad 65 -> banks (h+e)%32, 2-way = free
    __shared__ float keys_tile[16][EDIM];  // row-contiguous, reads are wave-broadcast
    __shared__ float h0t[16][H1D];
    __shared__ float part[16 * 256];       // layer2 partials [s][t], stride-1 rw
    __shared__ float scores[112];
    __shared__ float red[256];

    const int len = klen[b];
    const float* qrow = query + (size_t)b * EDIM;
    const float* krow = keys + (size_t)b * SEQ * EDIM;

    if (t < EDIM) q_lds[t] = qrow[t];
    __syncthreads();

    // ---- per-thread register weights for layer2/3 ----
    // thread t: column j = t&63 of W1/W2, h-range [hb*32, hb*32+32)
    const int j  = t & 63;
    const int hb = t >> 6;
    float w1r[32];
#pragma unroll
    for (int i = 0; i < 32; ++i)
        w1r[i] = W1[(hb * 32 + i) * H2D + j];   // coalesced over j
    const float b1r = b1[j];
    const float w2r = W2[j];
    const float b2r = b2[0];

    // ---- A[h] = b0[h] + sum_e q[e]*(W0q[e,h] + W0d[e,h]) ----
    if (t < H1D) {
        float acc = b0[t];
        for (int e = 0; e < EDIM; ++e)
            acc += q_lds[e] * (W0[e * H1D + t] + W0[(192 + e) * H1D + t]);
        A_h[t] = acc;
    }
    // ---- M^T[h][e] = W0k[e,h] - W0d[e,h] + q[e]*W0p[e,h] ----
    {
        const int h = t & 127;
        const int ebase = t >> 7;
#pragma unroll
        for (int i = 0; i < 32; ++i) {
            int e = i * 2 + ebase;
            float v = W0[(64 + e) * H1D + h] - W0[(192 + e) * H1D + h]
                    + q_lds[e] * W0[(128 + e) * H1D + h];
            MT[h][e] = v;
        }
    }
    __syncthreads();

    // ---- main loop over 7 s-tiles of 16 rows (rows >= 100 are zero-padded, masked later) ----
    for (int st = 0; st < 7; ++st) {
        const int s0 = st * 16;
        // load keys tile (tile is 4KB contiguous): thread t loads float4 #t
        {
            int row = s0 + (t >> 4);
            int col = (t & 15) * 4;
            float4 k4 = make_float4(0.f, 0.f, 0.f, 0.f);
            if (row < SEQ)
                k4 = *reinterpret_cast<const float4*>(krow + row * EDIM + col);
            *reinterpret_cast<float4*>(&keys_tile[t >> 4][col]) = k4;
        }
        __syncthreads();

        // layer1: h0[s][h] = relu(A[h] + sum_e keys[s][e]*MT[h][e])
        {
            const int h  = t & 127;
            const int sg = (t >> 7) * 8;   // 8 s-rows per thread
            float acc[8];
            const float a0 = A_h[h];
#pragma unroll
            for (int si = 0; si < 8; ++si) acc[si] = a0;
            for (int e4 = 0; e4 < EDIM; e4 += 4) {
                float m0 = MT[h][e4], m1 = MT[h][e4 + 1],
                      m2 = MT[h][e4 + 2], m3 = MT[h][e4 + 3];
#pragma unroll
                for (int si = 0; si < 8; ++si) {
                    float4 k = *reinterpret_cast<const float4*>(&keys_tile[sg + si][e4]);
                    acc[si] = fmaf(m0, k.x, acc[si]);
                    acc[si] = fmaf(m1, k.y, acc[si]);
                    acc[si] = fmaf(m2, k.z, acc[si]);
                    acc[si] = fmaf(m3, k.w, acc[si]);
                }
            }
#pragma unroll
            for (int si = 0; si < 8; ++si)
                h0t[sg + si][h] = fmaxf(acc[si], 0.f);
        }
        __syncthreads();

        // layer2 partials: part[s][t] = sum_{h in hb-range} h0[s][h]*W1[h][j]
        for (int s = 0; s < 16; ++s) {
            float acc = 0.f;
#pragma unroll
            for (int i4 = 0; i4 < 32; i4 += 4) {
                float4 hv = *reinterpret_cast<const float4*>(&h0t[s][hb * 32 + i4]);
                acc = fmaf(hv.x, w1r[i4],     acc);
                acc = fmaf(hv.y, w1r[i4 + 1], acc);
                acc = fmaf(hv.z, w1r[i4 + 2], acc);
                acc = fmaf(hv.w, w1r[i4 + 3], acc);
            }
            part[s * 256 + t] = acc;
        }
        __syncthreads();

        // reduce partials, relu, layer3 dot with W2, wave-reduce over j -> scores
#pragma unroll
        for (int pass = 0; pass < 4; ++pass) {
            int s = pass * 4 + wave;
            float v = b1r + part[s * 256 + j] + part[s * 256 + 64 + j]
                    + part[s * 256 + 128 + j] + part[s * 256 + 192 + j];
            v = fmaxf(v, 0.f);
            float sc = v * w2r;
#pragma unroll
            for (int off = 32; off; off >>= 1)
                sc += __shfl_xor(sc, off, 64);
            if (lane == 0) scores[s0 + s] = sc + b2r;
        }
        __syncthreads();
    }

    // ---- masked softmax over scores[0..99] (wave 0) ----
    if (wave == 0) {
        float v0 = (lane < len) ? scores[lane] : -INFINITY;
        int s1 = lane + 64;
        float v1 = (s1 < len) ? scores[s1] : -INFINITY;
        float m = fmaxf(v0, v1);
#pragma unroll
        for (int off = 32; off; off >>= 1)
            m = fmaxf(m, __shfl_xor(m, off, 64));
        float e0 = (lane < len) ? expf(v0 - m) : 0.f;
        float e1 = (s1 < len) ? expf(v1 - m) : 0.f;
        float ssum = e0 + e1;
#pragma unroll
        for (int off = 32; off; off >>= 1)
            ssum += __shfl_xor(ssum, off, 64);
        float inv = 1.f / ssum;
        scores[lane] = e0 * inv;
        if (s1 < 112) scores[s1] = e1 * inv;
    }
    __syncthreads();

    // ---- outputs ----
    if (t < SEQ) attn[(size_t)b * SEQ + t] = scores[t];

    // out[e] = sum_s attn[s]*keys[s][e]; 4 waves split s-range, e = lane
    {
        float acc = 0.f;
        const int e = j;
        for (int s = wave * 25; s < wave * 25 + 25; ++s)
            acc = fmaf(scores[s], krow[s * EDIM + e], acc);
        red[t] = acc;
    }
    __syncthreads();
    if (t < EDIM)
        out[(size_t)b * EDIM + t] = red[t] + red[64 + t] + red[128 + t] + red[192 + t];
}

extern "C" void kernel_launch(void* const* d_in, const int* in_sizes, int n_in,
                              void* d_out, int out_size, void* d_ws, size_t ws_size,
                              hipStream_t stream)
{
    const float* query = (const float*)d_in[0];
    const float* keys  = (const float*)d_in[1];
    const int*   klen  = (const int*)d_in[2];
    const float* W0 = (const float*)d_in[3];
    const float* b0 = (const float*)d_in[4];
    const float* W1 = (const float*)d_in[5];
    const float* b1 = (const float*)d_in[6];
    const float* W2 = (const float*)d_in[7];
    const float* b2 = (const float*)d_in[8];

    float* out  = (float*)d_out;                    // [B,64]
    float* attn = out + (size_t)B_TOT * EDIM;       // [B,100]

    din_fused<<<dim3(B_TOT), dim3(256), 0, stream>>>(
        query, keys, klen, W0, b0, W1, b1, W2, b2, out, attn);
}

// Round 3
// 868.147 us; speedup vs baseline: 1.2089x; 1.2089x over previous
//
#include <hip/hip_runtime.h>
#include <math.h>

// DIN attention, register-tiled f32 version.
// feats@W0 = A[b,h] + k @ M[b]  (M[e,h] = W0k - W0d + q_e*W0p;  A = b0 + q@(W0q+W0d))
// Per block b: layer1 GEMM [56x64]@[64x128] reg-tiled 7sx4h; layer2 [56x128]@[128x64]
// reg-tiled 7sx2j with W1 from global (L1); scores via shfl reduce; unnormalized
// softmax p=exp(score) (|score|<~5, no overflow); PV fused per s-tile from LDS keys.

#define B_TOT 8192
#define SEQ 100
#define EDIM 64
#define H1D 128
#define H2D 64
#define STILE 56
#define KPAD 68   // keys row stride (floats): breaks bank aliasing, keeps 16B align

#define F4C(v, i) ((i) == 0 ? (v).x : ((i) == 1 ? (v).y : ((i) == 2 ? (v).z : (v).w)))

__global__ __launch_bounds__(256, 2)
void din_fused(const float* __restrict__ query,
               const float* __restrict__ keys,
               const int* __restrict__ klen,
               const float* __restrict__ W0,
               const float* __restrict__ b0,
               const float* __restrict__ W1,
               const float* __restrict__ b1,
               const float* __restrict__ W2,
               const float* __restrict__ b2,
               float* __restrict__ out,
               float* __restrict__ attn)
{
    const int b = blockIdx.x;
    const int t = threadIdx.x;

    __shared__ float M_lds[64 * 128];      // M[e][h], h contiguous
    __shared__ float keys_t[STILE * KPAD]; // keys tile, padded rows
    __shared__ float h0[STILE * 128];      // layer1 output
    __shared__ float A_lds[128];
    __shared__ float q_lds[64];
    __shared__ float p_all[112];           // exp(score), masked rows = 0
    __shared__ float red[256];
    __shared__ float l_sh;

    const int len = klen[b];
    const float* qrow = query + (size_t)b * EDIM;
    const float* krow = keys + (size_t)b * SEQ * EDIM;

    if (t < 64) q_lds[t] = qrow[t];
    __syncthreads();

    // ---- build M[e][h] (all 256 threads) ----
    {
        const int h = t & 127, eb = t >> 7;
#pragma unroll
        for (int i = 0; i < 32; ++i) {
            int e = i * 2 + eb;
            M_lds[e * 128 + h] = W0[(64 + e) * 128 + h] - W0[(192 + e) * 128 + h]
                               + q_lds[e] * W0[(128 + e) * 128 + h];
        }
    }
    // ---- A[h] = b0 + q@(W0q+W0d) (wave 0+1) ----
    if (t < 128) {
        float a = b0[t];
        for (int e = 0; e < 64; ++e)
            a += q_lds[e] * (W0[e * 128 + t] + W0[(192 + e) * 128 + t]);
        A_lds[t] = a;
    }

    // per-thread constants: thread t -> jx = t&31 owns j = {2jx, 2jx+1}; syg = t>>5
    const int jx = t & 31;
    const int syg = t >> 5;
    const float b1a = b1[jx * 2], b1b = b1[jx * 2 + 1];
    const float w2a = W2[jx * 2], w2b = W2[jx * 2 + 1];
    const float b2v = b2[0];
    float out_acc = 0.f;
    __syncthreads();

    for (int tile = 0; tile < 2; ++tile) {
        const int s0 = tile * STILE;

        // ---- stage keys tile (zero-fill rows >= SEQ) ----
#pragma unroll
        for (int i = 0; i < 4; ++i) {
            int idx = i * 256 + t;
            if (idx < STILE * 16) {
                int r = idx >> 4, c = (idx & 15) * 4;
                int gs = s0 + r;
                float4 v = make_float4(0.f, 0.f, 0.f, 0.f);
                if (gs < SEQ) v = *reinterpret_cast<const float4*>(krow + gs * 64 + c);
                *reinterpret_cast<float4*>(&keys_t[r * KPAD + c]) = v;
            }
        }
        __syncthreads();

        // ---- layer1: h0[s][h] = relu(A[h] + sum_e K[s][e] * M[e][h]) ----
        // thread tile: s = syg*7+si (7 rows), h = jx*4..+3
        {
            float acc[7][4];
            float4 a4 = *reinterpret_cast<float4*>(&A_lds[jx * 4]);
#pragma unroll
            for (int si = 0; si < 7; ++si) {
                acc[si][0] = a4.x; acc[si][1] = a4.y; acc[si][2] = a4.z; acc[si][3] = a4.w;
            }
#pragma unroll 2
            for (int ec = 0; ec < 16; ++ec) {
                float4 kc[7], mm[4];
#pragma unroll
                for (int si = 0; si < 7; ++si)
                    kc[si] = *reinterpret_cast<float4*>(&keys_t[(syg * 7 + si) * KPAD + ec * 4]);
#pragma unroll
                for (int ei = 0; ei < 4; ++ei)
                    mm[ei] = *reinterpret_cast<float4*>(&M_lds[(ec * 4 + ei) * 128 + jx * 4]);
#pragma unroll
                for (int ei = 0; ei < 4; ++ei) {
#pragma unroll
                    for (int si = 0; si < 7; ++si) {
                        float k = F4C(kc[si], ei);
                        acc[si][0] = fmaf(k, mm[ei].x, acc[si][0]);
                        acc[si][1] = fmaf(k, mm[ei].y, acc[si][1]);
                        acc[si][2] = fmaf(k, mm[ei].z, acc[si][2]);
                        acc[si][3] = fmaf(k, mm[ei].w, acc[si][3]);
                    }
                }
            }
#pragma unroll
            for (int si = 0; si < 7; ++si) {
                float4 r;
                r.x = fmaxf(acc[si][0], 0.f); r.y = fmaxf(acc[si][1], 0.f);
                r.z = fmaxf(acc[si][2], 0.f); r.w = fmaxf(acc[si][3], 0.f);
                *reinterpret_cast<float4*>(&h0[(syg * 7 + si) * 128 + jx * 4]) = r;
            }
        }
        __syncthreads();

        // ---- layer2 + scores: h1[s][j] = relu(b1 + h0[s]@W1[:,j]); score = h1@W2 ----
        {
            float acc2[7][2];
#pragma unroll
            for (int si = 0; si < 7; ++si) { acc2[si][0] = 0.f; acc2[si][1] = 0.f; }
#pragma unroll 4
            for (int hc = 0; hc < 32; ++hc) {
                float4 hv[7];
#pragma unroll
                for (int si = 0; si < 7; ++si)
                    hv[si] = *reinterpret_cast<float4*>(&h0[(syg * 7 + si) * 128 + hc * 4]);
                float2 w[4];
#pragma unroll
                for (int i = 0; i < 4; ++i)
                    w[i] = *reinterpret_cast<const float2*>(&W1[(hc * 4 + i) * 64 + jx * 2]);
#pragma unroll
                for (int i = 0; i < 4; ++i) {
#pragma unroll
                    for (int si = 0; si < 7; ++si) {
                        float hvv = F4C(hv[si], i);
                        acc2[si][0] = fmaf(hvv, w[i].x, acc2[si][0]);
                        acc2[si][1] = fmaf(hvv, w[i].y, acc2[si][1]);
                    }
                }
            }
#pragma unroll
            for (int si = 0; si < 7; ++si) {
                float v = fmaxf(acc2[si][0] + b1a, 0.f) * w2a
                        + fmaxf(acc2[si][1] + b1b, 0.f) * w2b;
#pragma unroll
                for (int off = 1; off < 32; off <<= 1)
                    v += __shfl_xor(v, off, 64);
                int gs = s0 + syg * 7 + si;
                if (jx == 0)
                    p_all[gs] = (gs < len) ? expf(v + b2v) : 0.f;
            }
        }
        __syncthreads();

        // ---- PV partial: out_acc[e] += sum_s p[s]*keys[s][e] ----
        {
            const int e = t & 63, sg = t >> 6;
#pragma unroll
            for (int si = 0; si < 14; ++si) {
                int sl = sg * 14 + si;
                out_acc = fmaf(p_all[s0 + sl], keys_t[sl * KPAD + e], out_acc);
            }
        }
        __syncthreads();   // keys_t/h0 reused next tile
    }

    red[t] = out_acc;
    __syncthreads();
    if (t < 64) {
        float v = p_all[t] + (t < 48 ? p_all[64 + t] : 0.f);
#pragma unroll
        for (int off = 1; off < 64; off <<= 1)
            v += __shfl_xor(v, off, 64);
        if (t == 0) l_sh = v;
    }
    __syncthreads();
    const float linv = 1.f / l_sh;
    if (t < 64)
        out[(size_t)b * 64 + t] = (red[t] + red[64 + t] + red[128 + t] + red[192 + t]) * linv;
    if (t < 100)
        attn[(size_t)b * 100 + t] = p_all[t] * linv;
}

extern "C" void kernel_launch(void* const* d_in, const int* in_sizes, int n_in,
                              void* d_out, int out_size, void* d_ws, size_t ws_size,
                              hipStream_t stream)
{
    const float* query = (const float*)d_in[0];
    const float* keys  = (const float*)d_in[1];
    const int*   klen  = (const int*)d_in[2];
    const float* W0 = (const float*)d_in[3];
    const float* b0 = (const float*)d_in[4];
    const float* W1 = (const float*)d_in[5];
    const float* b1 = (const float*)d_in[6];
    const float* W2 = (const float*)d_in[7];
    const float* b2 = (const float*)d_in[8];

    float* out  = (float*)d_out;                    // [B,64]
    float* attn = out + (size_t)B_TOT * EDIM;       // [B,100]

    din_fused<<<dim3(B_TOT), dim3(256), 0, stream>>>(
        query, keys, klen, W0, b0, W1, b1, W2, b2, out, attn);
}